// Round 5
// baseline (54.845 us; speedup 1.0000x reference)
//
#include <hip/hip_runtime.h>
#include <stdint.h>

typedef __attribute__((ext_vector_type(8))) short short8;
typedef __attribute__((ext_vector_type(4))) float f32x4;
typedef __attribute__((ext_vector_type(4))) uint32_t u32x4;

#define K_DIM 4096
#define N_DIM 128
#define M_DIM 4096
#define MN ((size_t)M_DIM * N_DIM)
#define NS 8
#define FRAG_PER_SLAB ((size_t)64 * 8192)   // 64 m-tiles x (4 waves*64 lanes*32 vals)

__device__ __forceinline__ uint16_t f2bf(float f) {
    uint32_t u = __float_as_uint(f);
    return (uint16_t)((u + 0x7FFFu + ((u >> 16) & 1u)) >> 16);
}
__device__ __forceinline__ float bf2f(uint16_t h) {
    return __uint_as_float((uint32_t)h << 16);
}

__device__ __forceinline__ short8 cvt8(const float4 lo, const float4 hi) {
    short8 r;
    r[0] = (short)f2bf(lo.x); r[1] = (short)f2bf(lo.y);
    r[2] = (short)f2bf(lo.z); r[3] = (short)f2bf(lo.w);
    r[4] = (short)f2bf(hi.x); r[5] = (short)f2bf(hi.y);
    r[6] = (short)f2bf(hi.z); r[7] = (short)f2bf(hi.w);
    return r;
}

// ---- prep: W f32 -> bf16 (3 matrices of 128 x 4096) ----
__global__ __launch_bounds__(256) void prep_kernel(
    const float* __restrict__ W0, const float* __restrict__ W1,
    const float* __restrict__ W2, uint16_t* __restrict__ Wb)
{
    int gid = blockIdx.x * 256 + threadIdx.x;   // 0 .. 196607
    int g = gid >> 16;                          // 65536 threads per matrix
    int e = (gid & 65535) * 8;
    const float* W = (g == 0) ? W0 : (g == 1) ? W1 : W2;
    float4 lo = *(const float4*)(W + e);
    float4 hi = *(const float4*)(W + e + 4);
    *(short8*)(Wb + (size_t)g * (N_DIM * K_DIM) + e) = cvt8(lo, hi);
}

// ---- GEMM, K-split NS=8: R0's verified per-iteration structure (BM=64,
// BN=128, BK=64: 16 MFMA + 8 ds_read_b128 + 4 global_load_lds per wave per
// barrier, 0 bank conflicts). 1536 blocks -> 5 resident blocks/CU (LDS-capped),
// independent barriers overlap (m114). Partials stored bf16 FRAGMENT-PACKED:
// each lane writes its 32 acc values as 4 contiguous 16B stores.
__global__ __launch_bounds__(256) void gemm3_kernel(
    const float* __restrict__ x0, const float* __restrict__ x1,
    const float* __restrict__ x2, const uint16_t* __restrict__ Wb,
    uint16_t* __restrict__ zpart)
{
    __shared__ uint16_t lds[2][8192];   // 2 x 16 KiB: [col(128)][granule(8) of 8 bf16]

    const int tid  = threadIdx.x;
    const int lane = tid & 63;
    const int wv   = tid >> 6;

    const int per = (192 * NS) >> 3;                 // blocks per XCD (=192)
    const int lid = (blockIdx.x & 7) * per + (blockIdx.x >> 3);
    const int g   = lid / (NS * 64);
    const int rem = lid % (NS * 64);
    const int ks  = rem >> 6;
    const int mt  = rem & 63;
    const int k0  = ks * (K_DIM / NS);               // K-chunk of 512
    const int NT  = (K_DIM / NS) / 64;               // 8 iterations

    const float* x = (g == 0) ? x0 : (g == 1) ? x1 : x2;
    const uint16_t* Wg = Wb + (size_t)g * (N_DIM * K_DIM);

    const int c16 = lane & 15;
    const int qg  = lane >> 4;
    const int rowbase = mt * 64 + wv * 16;
    const float* aptr = x + (size_t)(rowbase + c16) * K_DIM + qg * 8 + k0;

    // staging source per call c: col = c*32 + (tid>>3), slot = tid&7, granule = slot ^ (col&7)
    const int t8 = tid >> 3, slot = tid & 7;
    const uint16_t* wsrc[4];
#pragma unroll
    for (int c = 0; c < 4; ++c) {
        int col = c * 32 + t8;
        wsrc[c] = Wg + (size_t)col * K_DIM + (slot ^ (col & 7)) * 8 + k0;
    }

    f32x4 acc[8];
#pragma unroll
    for (int nf = 0; nf < 8; ++nf) acc[nf] = (f32x4)0.f;

    auto stage = [&](int p, int kbase) {
#pragma unroll
        for (int c = 0; c < 4; ++c) {
            __builtin_amdgcn_global_load_lds(
                (const __attribute__((address_space(1))) uint32_t*)(wsrc[c] + kbase),
                (__attribute__((address_space(3))) uint32_t*)&lds[p][c * 2048 + wv * 512],
                16, 0, 0);
        }
    };

    stage(0, 0);
    float4 a_cur[4], a_nxt[4];
    a_cur[0] = *(const float4*)(aptr);
    a_cur[1] = *(const float4*)(aptr + 4);
    a_cur[2] = *(const float4*)(aptr + 32);
    a_cur[3] = *(const float4*)(aptr + 36);

    int p = 0;
    for (int kt = 0; kt < NT; ++kt) {
        const int kbase = kt * 64;
        __syncthreads();            // staging of buffer p (and A prefetch) complete
        if (kt + 1 < NT) {
            stage(p ^ 1, kbase + 64);
            const float* ap = aptr + kbase + 64;
            a_nxt[0] = *(const float4*)(ap);
            a_nxt[1] = *(const float4*)(ap + 4);
            a_nxt[2] = *(const float4*)(ap + 32);
            a_nxt[3] = *(const float4*)(ap + 36);
        }
#pragma unroll
        for (int h = 0; h < 2; ++h) {           // kk = 32*h
            short8 af = cvt8(a_cur[2 * h], a_cur[2 * h + 1]);
            const int boff = c16 * 64 + (((h * 4) + qg) ^ (lane & 7)) * 8;
#pragma unroll
            for (int nf = 0; nf < 8; ++nf) {
                short8 bf = *(const short8*)&lds[p][nf * 1024 + boff];
                acc[nf] = __builtin_amdgcn_mfma_f32_16x16x32_bf16(af, bf, acc[nf], 0, 0, 0);
            }
        }
#pragma unroll
        for (int i = 0; i < 4; ++i) a_cur[i] = a_nxt[i];
        p ^= 1;
    }

    // fragment-packed bf16 epilogue: idx = nf*4 + r, 32 vals per lane, 64B contiguous
    uint32_t dw[16];
#pragma unroll
    for (int nf = 0; nf < 8; ++nf) {
        dw[nf * 2]     = (uint32_t)f2bf(acc[nf][0]) | ((uint32_t)f2bf(acc[nf][1]) << 16);
        dw[nf * 2 + 1] = (uint32_t)f2bf(acc[nf][2]) | ((uint32_t)f2bf(acc[nf][3]) << 16);
    }
    uint16_t* zp = zpart + (size_t)(ks * 3 + g) * FRAG_PER_SLAB
                 + (size_t)mt * 8192 + (size_t)(wv * 64 + lane) * 32;
    uint32_t* zp32 = (uint32_t*)zp;
#pragma unroll
    for (int j = 0; j < 4; ++j) {
        u32x4 v = { dw[j * 4], dw[j * 4 + 1], dw[j * 4 + 2], dw[j * 4 + 3] };
        *(u32x4*)(zp32 + j * 4) = v;
    }
}

// ---- combine: sum 8 bf16 partials per (g, element) in fragment order,
// write aligned (scatter decode), per-block loss partials ----
__global__ __launch_bounds__(256) void combine_kernel(
    const uint16_t* __restrict__ zpart, float* __restrict__ out,
    float* __restrict__ partials)
{
    const int tid  = threadIdx.x;
    const int gtid = blockIdx.x * 256 + tid;        // 65536 threads
    const size_t F0 = (size_t)gtid * 8;             // 8 consecutive frag vals

    // decode fragment position
    const int idx_base = (int)(F0 & 31);            // 0,8,16,24
    const int lane = (int)((F0 >> 5) & 63);
    const int wv   = (int)((F0 >> 11) & 3);
    const int mt   = (int)(F0 >> 13);
    const int c16  = lane & 15;
    const int qg   = lane >> 4;
    const int rowb = mt * 64 + wv * 16 + qg * 4;

    float zs[3][8];
#pragma unroll
    for (int g = 0; g < 3; ++g)
#pragma unroll
        for (int v = 0; v < 8; ++v) zs[g][v] = 0.f;

#pragma unroll
    for (int ks = 0; ks < NS; ++ks) {
#pragma unroll
        for (int g = 0; g < 3; ++g) {
            const short8 pv = *(const short8*)(zpart + (size_t)(ks * 3 + g) * FRAG_PER_SLAB + F0);
#pragma unroll
            for (int v = 0; v < 8; ++v) zs[g][v] += bf2f((uint16_t)pv[v]);
        }
    }

    float s = 0.f;
#pragma unroll
    for (int v = 0; v < 8; ++v) {
        const float a = zs[0][v], b = zs[1][v], c = zs[2][v];
        const int idx = idx_base + v;
        const int nf = idx >> 2, r = idx & 3;
        out[(size_t)(rowb + r) * N_DIM + nf * 16 + c16] = (a + b + c) * (1.f / 3.f);
        const float d1 = a - b, d2 = a - c, d3 = b - c;
        s += d1 * d1 + d2 * d2 + d3 * d3;
    }

#pragma unroll
    for (int off = 32; off > 0; off >>= 1) s += __shfl_xor(s, off);
    __shared__ float wsum[4];
    if ((tid & 63) == 0) wsum[tid >> 6] = s;
    __syncthreads();
    if (tid == 0) partials[blockIdx.x] = wsum[0] + wsum[1] + wsum[2] + wsum[3];
}

__global__ __launch_bounds__(256) void finalize_kernel(
    const float* __restrict__ partials, float* __restrict__ out)
{
    const int tid = threadIdx.x;
    float s = partials[tid];
#pragma unroll
    for (int off = 32; off > 0; off >>= 1) s += __shfl_xor(s, off);
    __shared__ float wsum[4];
    if ((tid & 63) == 0) wsum[tid >> 6] = s;
    __syncthreads();
    if (tid == 0)
        out[MN] = (wsum[0] + wsum[1] + wsum[2] + wsum[3]) * (1.f / 12288.f) - 0.05f;
}

extern "C" void kernel_launch(void* const* d_in, const int* in_sizes, int n_in,
                              void* d_out, int out_size, void* d_ws, size_t ws_size,
                              hipStream_t stream)
{
    const float* x0 = (const float*)d_in[0];
    const float* x1 = (const float*)d_in[1];
    const float* x2 = (const float*)d_in[2];
    const float* W0 = (const float*)d_in[3];
    const float* W1 = (const float*)d_in[4];
    const float* W2 = (const float*)d_in[5];
    float* out = (float*)d_out;

    const size_t zpart_bytes = (size_t)NS * 3 * FRAG_PER_SLAB * sizeof(uint16_t); // 25,165,824
    const size_t wb_bytes    = (size_t)3 * N_DIM * K_DIM * sizeof(uint16_t);      //  3,145,728

    char* ws = (char*)d_ws;
    uint16_t* zpart    = (uint16_t*)ws;
    uint16_t* Wb       = (uint16_t*)(ws + zpart_bytes);
    float*    partials = (float*)(ws + zpart_bytes + wb_bytes);

    prep_kernel    <<< 768, 256, 0, stream>>>(W0, W1, W2, Wb);
    gemm3_kernel   <<<1536, 256, 0, stream>>>(x0, x1, x2, Wb, zpart);
    combine_kernel <<< 256, 256, 0, stream>>>(zpart, out, partials);
    finalize_kernel<<<   1, 256, 0, stream>>>(partials, out);
}